// Round 5
// baseline (2690.077 us; speedup 1.0000x reference)
//
#include <hip/hip_runtime.h>

#define C 128

typedef __attribute__((ext_vector_type(8))) short short8v;
typedef __attribute__((ext_vector_type(4))) float float4v;

__device__ __forceinline__ ushort f2bf(float f) {
  union { float f; uint u; } v; v.f = f;
  uint u = v.u;
  return (ushort)((u + 0x7FFF + ((u >> 16) & 1)) >> 16);  // RNE
}
__device__ __forceinline__ float bf2f(ushort s) {
  union { uint u; float f; } v; v.u = ((uint)s) << 16; return v.f;
}

// LDS swizzles: row-stride 128 shorts (16 chunks of 8) / 64 shorts (8 chunks)
__device__ __forceinline__ short* swz(short* base, int row, int chunk) {
  return base + row * 128 + ((chunk ^ (row & 15)) << 3);
}
__device__ __forceinline__ short* swz8(short* base, int row, int chunk) {
  return base + row * 64 + ((chunk ^ (row & 7)) << 3);
}

// ---------------- degree count ------------------------------------------
__global__ void k_degree(const int* __restrict__ col, int* __restrict__ cnt, int E) {
  int e = blockIdx.x * blockDim.x + threadIdx.x;
  if (e < E) atomicAdd(&cnt[col[e]], 1);
}

// ---------------- single-block scan: deg -> dis, indptr, cursor --------
__global__ void k_scan(const int* __restrict__ cnt, float* __restrict__ dis,
                       int* __restrict__ indptr, int* __restrict__ cursor, int N) {
  __shared__ int sb[1024];
  int t = threadIdx.x;
  int chunk = (N + 1023) >> 10;
  int lo = t * chunk, hi = min(lo + chunk, N);
  int sum = 0;
  for (int i = lo; i < hi; ++i) sum += cnt[i];
  sb[t] = sum;
  __syncthreads();
  for (int off = 1; off < 1024; off <<= 1) {
    int v = (t >= off) ? sb[t - off] : 0;
    __syncthreads();
    sb[t] += v;
    __syncthreads();
  }
  int run = sb[t] - sum;
  for (int i = lo; i < hi; ++i) {
    indptr[i] = run; cursor[i] = run;
    dis[i] = rsqrtf((float)(cnt[i] + 1));
    run += cnt[i];
  }
  if (lo < N && hi == N) indptr[N] = run;
}

// ---------------- CSR fill: dst-sorted {src,norm}, {src,dst}, edge-id ---
__global__ void k_csrfill(const int* __restrict__ row, const int* __restrict__ col,
                          const float* __restrict__ dis, int* __restrict__ cursor,
                          int2* __restrict__ emeta, int2* __restrict__ epair,
                          int* __restrict__ eid, int E) {
  int e = blockIdx.x * blockDim.x + threadIdx.x;
  if (e >= E) return;
  int r = row[e], c = col[e];
  int pos = atomicAdd(&cursor[c], 1);
  float nrm = dis[r] * dis[c];
  emeta[pos] = make_int2(r, __float_as_int(nrm));
  epair[pos] = make_int2(r, c);
  eid[pos] = e;
}

// ---------------- W1^T -> bf16 (fc1, hi only) ---------------------------
__global__ void k_prepw(const float* __restrict__ W1, ushort* __restrict__ W1t) {
  int idx = blockIdx.x * 256 + threadIdx.x;  // 16384
  int n = idx >> 7, k = idx & 127;
  W1t[idx] = f2bf(W1[k * C + n]);
}

// ---------------- conv/fc0 W^T -> bf16 hi/lo (10 matrices) --------------
__global__ void k_prepw2(const float* __restrict__ convs_W,
                         const float* __restrict__ fc0_W,
                         ushort* __restrict__ Wth, ushort* __restrict__ Wtl) {
  int g = blockIdx.x * 256 + threadIdx.x;  // [0, 10*16384)
  int mat = g >> 14, idx = g & 16383;
  int n = idx >> 7, k = idx & 127;
  const float* src = (mat < 8) ? convs_W + ((size_t)mat << 14)
                               : fc0_W + ((size_t)(mat - 8) << 14);
  float v = src[k * C + n];
  ushort h = f2bf(v);
  Wth[g] = h;
  Wtl[g] = f2bf(v - bf2f(h));
}

// ---------------- fused conv layer: aggregate + MFMA GEMM ---------------
// Block = 64 dst nodes, 4 waves. Wave w aggregates its own 16 M-rows
// (lane = channel pair) straight into the hi/lo A-LDS tile (no cross-wave
// dep), then the k_gemm_mfma MFMA phase runs on it. out = relu(agg@W+b[+skip]).
__global__ __launch_bounds__(256, 2)
void k_layer(const float* __restrict__ h, const int* __restrict__ indptr,
             const int2* __restrict__ emeta, const float* __restrict__ dis,
             const ushort* __restrict__ Wth, const ushort* __restrict__ Wtl,
             const float* __restrict__ bias, const float* __restrict__ skip,
             float* __restrict__ out, int N) {
  __shared__ __align__(16) short Ah[64 * 128];
  __shared__ __align__(16) short Al[64 * 128];
  __shared__ __align__(16) short Wh[128 * 64];
  __shared__ __align__(16) short Wl[128 * 64];
  int t = threadIdx.x;
  int r0 = blockIdx.x * 64;
  int w = t >> 6, lane = t & 63;

  // phase 1: aggregate this wave's 16 rows -> hi/lo bf16 LDS
  for (int nl = 0; nl < 16; ++nl) {
    int g = r0 + w * 16 + nl;
    float ax = 0.f, ay = 0.f;
    if (g < N) {
      int s = indptr[g], e = indptr[g + 1];
      int i = s;
      for (; i + 4 <= e; i += 4) {
        int2 m0 = emeta[i], m1 = emeta[i + 1], m2 = emeta[i + 2], m3 = emeta[i + 3];
        float2 h0 = *(const float2*)(h + (size_t)m0.x * C + lane * 2);
        float2 h1 = *(const float2*)(h + (size_t)m1.x * C + lane * 2);
        float2 h2 = *(const float2*)(h + (size_t)m2.x * C + lane * 2);
        float2 h3 = *(const float2*)(h + (size_t)m3.x * C + lane * 2);
        float n0 = __int_as_float(m0.y), n1 = __int_as_float(m1.y);
        float n2 = __int_as_float(m2.y), n3 = __int_as_float(m3.y);
        ax += n0 * h0.x + n1 * h1.x + n2 * h2.x + n3 * h3.x;
        ay += n0 * h0.y + n1 * h1.y + n2 * h2.y + n3 * h3.y;
      }
      for (; i < e; ++i) {
        int2 m0 = emeta[i];
        float2 h0 = *(const float2*)(h + (size_t)m0.x * C + lane * 2);
        float n0 = __int_as_float(m0.y);
        ax += n0 * h0.x; ay += n0 * h0.y;
      }
      float dv = dis[g];
      float2 hs = *(const float2*)(h + (size_t)g * C + lane * 2);
      ax += dv * dv * hs.x; ay += dv * dv * hs.y;
    }
    ushort hx = f2bf(ax), hy = f2bf(ay);
    ushort lx = f2bf(ax - bf2f(hx)), ly = f2bf(ay - bf2f(hy));
    int rowl = w * 16 + nl;
    short* ph = swz(Ah, rowl, lane >> 2) + (lane & 3) * 2;
    short* pl = swz(Al, rowl, lane >> 2) + (lane & 3) * 2;
    *(uint*)ph = (uint)hx | ((uint)hy << 16);
    *(uint*)pl = (uint)lx | ((uint)ly << 16);
  }

  // phase 2: MFMA, W staged in two k-halves
  int m0 = w * 16;
  int lm = lane & 15, lq = lane >> 4;
  float4v acc[8];
#pragma unroll
  for (int j = 0; j < 8; ++j) acc[j] = (float4v){0.f, 0.f, 0.f, 0.f};

  for (int half = 0; half < 2; ++half) {
    __syncthreads();
    {
#pragma unroll
      for (int i = 0; i < 4; ++i) {
        int gi = i * 256 + t;            // chunk id 0..1023
        int n = gi >> 3, kc = gi & 7;
        size_t off = (size_t)n * 128 + half * 64 + kc * 8;
        *(short8v*)swz8(Wh, n, kc) = *(const short8v*)(Wth + off);
        *(short8v*)swz8(Wl, n, kc) = *(const short8v*)(Wtl + off);
      }
    }
    __syncthreads();
#pragma unroll
    for (int kk = 0; kk < 2; ++kk) {
      int ach = (half * 2 + kk) * 4 + lq;
      int wch = kk * 4 + lq;
      short8v ah = *(const short8v*)swz(Ah, m0 + lm, ach);
      short8v al = *(const short8v*)swz(Al, m0 + lm, ach);
#pragma unroll
      for (int j = 0; j < 8; ++j) {
        short8v bh = *(const short8v*)swz8(Wh, j * 16 + lm, wch);
        short8v bl = *(const short8v*)swz8(Wl, j * 16 + lm, wch);
        acc[j] = __builtin_amdgcn_mfma_f32_16x16x32_bf16(ah, bh, acc[j], 0, 0, 0);
        acc[j] = __builtin_amdgcn_mfma_f32_16x16x32_bf16(al, bh, acc[j], 0, 0, 0);
        acc[j] = __builtin_amdgcn_mfma_f32_16x16x32_bf16(ah, bl, acc[j], 0, 0, 0);
      }
    }
  }
  // epilogue: D row = lq*4+r, col = j*16+lm
#pragma unroll
  for (int j = 0; j < 8; ++j) {
    int n = j * 16 + lm;
    float bv = bias[n];
#pragma unroll
    for (int r = 0; r < 4; ++r) {
      int m = r0 + m0 + lq * 4 + r;
      if (m >= N) continue;
      float v = acc[j][r] + bv;
      if (skip) v += skip[(size_t)m * C + n];
      v = fmaxf(v, 0.f);
      out[(size_t)m * C + n] = v;
    }
  }
}

// ---------------- MFMA GEMM (dense, for P/Q) ----------------------------
__global__ __launch_bounds__(256, 2)
void k_gemm_mfma(const float* __restrict__ A, const ushort* __restrict__ Wth,
                 const ushort* __restrict__ Wtl, const float* __restrict__ bias,
                 float* __restrict__ out, int M) {
  __shared__ __align__(16) short Ah[64 * 128];
  __shared__ __align__(16) short Al[64 * 128];
  __shared__ __align__(16) short Wh[128 * 64];
  __shared__ __align__(16) short Wl[128 * 64];
  int t = threadIdx.x;
  int r0 = blockIdx.x * 64;
  {
    int rl = t >> 2, p = t & 3;
    int r = r0 + rl;
    const float* Ar = A + (size_t)r * C + p * 32;
#pragma unroll
    for (int i = 0; i < 4; ++i) {
      float v[8];
      if (r < M) {
        float4 a0 = *(const float4*)(Ar + 8 * i);
        float4 a1 = *(const float4*)(Ar + 8 * i + 4);
        v[0] = a0.x; v[1] = a0.y; v[2] = a0.z; v[3] = a0.w;
        v[4] = a1.x; v[5] = a1.y; v[6] = a1.z; v[7] = a1.w;
      } else {
#pragma unroll
        for (int j = 0; j < 8; ++j) v[j] = 0.f;
      }
      short8v hi, lo;
#pragma unroll
      for (int j = 0; j < 8; ++j) {
        ushort hh = f2bf(v[j]);
        hi[j] = (short)hh;
        lo[j] = (short)f2bf(v[j] - bf2f(hh));
      }
      *(short8v*)swz(Ah, rl, p * 4 + i) = hi;
      *(short8v*)swz(Al, rl, p * 4 + i) = lo;
    }
  }
  int w = t >> 6, lane = t & 63;
  int m0 = w * 16;
  int lm = lane & 15, lq = lane >> 4;
  float4v acc[8];
#pragma unroll
  for (int j = 0; j < 8; ++j) acc[j] = (float4v){0.f, 0.f, 0.f, 0.f};

  for (int half = 0; half < 2; ++half) {
    __syncthreads();
    {
#pragma unroll
      for (int i = 0; i < 4; ++i) {
        int g = i * 256 + t;
        int n = g >> 3, kc = g & 7;
        size_t off = (size_t)n * 128 + half * 64 + kc * 8;
        *(short8v*)swz8(Wh, n, kc) = *(const short8v*)(Wth + off);
        *(short8v*)swz8(Wl, n, kc) = *(const short8v*)(Wtl + off);
      }
    }
    __syncthreads();
#pragma unroll
    for (int kk = 0; kk < 2; ++kk) {
      int ach = (half * 2 + kk) * 4 + lq;
      int wch = kk * 4 + lq;
      short8v ah = *(const short8v*)swz(Ah, m0 + lm, ach);
      short8v al = *(const short8v*)swz(Al, m0 + lm, ach);
#pragma unroll
      for (int j = 0; j < 8; ++j) {
        short8v bh = *(const short8v*)swz8(Wh, j * 16 + lm, wch);
        short8v bl = *(const short8v*)swz8(Wl, j * 16 + lm, wch);
        acc[j] = __builtin_amdgcn_mfma_f32_16x16x32_bf16(ah, bh, acc[j], 0, 0, 0);
        acc[j] = __builtin_amdgcn_mfma_f32_16x16x32_bf16(al, bh, acc[j], 0, 0, 0);
        acc[j] = __builtin_amdgcn_mfma_f32_16x16x32_bf16(ah, bl, acc[j], 0, 0, 0);
      }
    }
  }
#pragma unroll
  for (int j = 0; j < 8; ++j) {
    int n = j * 16 + lm;
    float bv = bias ? bias[n] : 0.f;
#pragma unroll
    for (int r = 0; r < 4; ++r) {
      int m = r0 + m0 + lq * 4 + r;
      if (m >= M) continue;
      out[(size_t)m * C + n] = acc[j][r] + bv;
    }
  }
}

// ---------------- fused edge MLP (CSR order) -----------------------------
// 64 CSR positions/block: dst nearly constant -> Q row L1-resident; P random.
// e1 = relu(P[src]+Q[dst]) hi/lo bf16 in LDS; MFMA fc1; fused relu+fc2 dot;
// scatter result to out[eid].
__global__ __launch_bounds__(256, 2)
void k_edge(const float* __restrict__ P, const float* __restrict__ Q,
            const int2* __restrict__ epair, const int* __restrict__ eid,
            const ushort* __restrict__ W1t, const float* __restrict__ b1,
            const float* __restrict__ w2, const float* __restrict__ b2,
            float* __restrict__ out, int E) {
  __shared__ __align__(16) short EtH[64 * 128];
  __shared__ __align__(16) short EtL[64 * 128];
  __shared__ __align__(16) short Wl[128 * 128];
  int t = threadIdx.x;
  int p0 = blockIdx.x * 64;
  {
    int el = t >> 2, p4 = t & 3;
    int p = p0 + el;
    if (p >= E) p = E - 1;
    int2 rc = epair[p];
    const float* Pp = P + (size_t)rc.x * C + p4 * 32;
    const float* Qp = Q + (size_t)rc.y * C + p4 * 32;
#pragma unroll
    for (int i = 0; i < 4; ++i) {
      float4 a0 = *(const float4*)(Pp + 8 * i);
      float4 a1 = *(const float4*)(Pp + 8 * i + 4);
      float4 b0 = *(const float4*)(Qp + 8 * i);
      float4 b1v4 = *(const float4*)(Qp + 8 * i + 4);
      float v[8] = {a0.x + b0.x, a0.y + b0.y, a0.z + b0.z, a0.w + b0.w,
                    a1.x + b1v4.x, a1.y + b1v4.y, a1.z + b1v4.z, a1.w + b1v4.w};
      short8v hi, lo;
#pragma unroll
      for (int j = 0; j < 8; ++j) {
        float f = fmaxf(v[j], 0.f);
        ushort h = f2bf(f);
        hi[j] = (short)h;
        lo[j] = (short)f2bf(f - bf2f(h));
      }
      *(short8v*)swz(EtH, el, p4 * 4 + i) = hi;
      *(short8v*)swz(EtL, el, p4 * 4 + i) = lo;
    }
  }
  {
#pragma unroll
    for (int i = 0; i < 8; ++i) {
      int g = i * 256 + t;
      int r = g >> 4, c = g & 15;
      short8v wv = *(const short8v*)(W1t + g * 8);
      *(short8v*)swz(Wl, r, c) = wv;
    }
  }
  __syncthreads();

  int w = t >> 6, lane = t & 63;
  int m0 = w * 16;
  int lm = lane & 15, lq = lane >> 4;
  float4v acc[8];
#pragma unroll
  for (int j = 0; j < 8; ++j) acc[j] = (float4v){0.f, 0.f, 0.f, 0.f};

#pragma unroll
  for (int kk = 0; kk < 4; ++kk) {
    int ch = kk * 4 + lq;
    short8v ah = *(const short8v*)swz(EtH, m0 + lm, ch);
    short8v al = *(const short8v*)swz(EtL, m0 + lm, ch);
#pragma unroll
    for (int j = 0; j < 8; ++j) {
      short8v b = *(const short8v*)swz(Wl, j * 16 + lm, ch);
      acc[j] = __builtin_amdgcn_mfma_f32_16x16x32_bf16(ah, b, acc[j], 0, 0, 0);
      acc[j] = __builtin_amdgcn_mfma_f32_16x16x32_bf16(al, b, acc[j], 0, 0, 0);
    }
  }

  float partv[4] = {0.f, 0.f, 0.f, 0.f};
#pragma unroll
  for (int j = 0; j < 8; ++j) {
    int n = j * 16 + lm;
    float b1v = b1[n], w2v = w2[n];
#pragma unroll
    for (int r = 0; r < 4; ++r) {
      float e2 = fmaxf(acc[j][r] + b1v, 0.f);
      partv[r] = fmaf(e2, w2v, partv[r]);
    }
  }
#pragma unroll
  for (int off = 1; off < 16; off <<= 1) {
#pragma unroll
    for (int r = 0; r < 4; ++r) partv[r] += __shfl_xor(partv[r], off, 64);
  }
  if (lm == 0) {
    float bb = b2[0];
#pragma unroll
    for (int r = 0; r < 4; ++r) {
      int p = p0 + m0 + lq * 4 + r;
      if (p < E) out[eid[p]] = partv[r] + bb;
    }
  }
}

// ---------------- host ---------------------------------------------------
extern "C" void kernel_launch(void* const* d_in, const int* in_sizes, int n_in,
                              void* d_out, int out_size, void* d_ws, size_t ws_size,
                              hipStream_t stream) {
  const float* x       = (const float*)d_in[0];
  const int*   ei      = (const int*)d_in[1];
  const float* convs_W = (const float*)d_in[2];
  const float* convs_b = (const float*)d_in[3];
  const float* fc0_W   = (const float*)d_in[4];
  const float* fc0_b   = (const float*)d_in[5];
  const float* fc1_W   = (const float*)d_in[6];
  const float* fc1_b   = (const float*)d_in[7];
  const float* fc2_W   = (const float*)d_in[8];
  const float* fc2_b   = (const float*)d_in[9];
  float* out = (float*)d_out;

  const int N = in_sizes[0] / C;        // 50000
  const int E = in_sizes[1] / 2;        // 1600000
  const int L = in_sizes[2] / (C * C);  // 8
  const int* row = ei;
  const int* col = ei + E;

  char* wp = (char*)d_ws;
  auto carve = [&](size_t bytes) {
    char* p = wp; wp += (bytes + 255) & ~(size_t)255; return p;
  };
  int*    cnt    = (int*)carve((size_t)N * 4);
  int*    indptr = (int*)carve((size_t)(N + 1) * 4);
  int*    cursor = (int*)carve((size_t)N * 4);
  float*  dis    = (float*)carve((size_t)N * 4);
  int2*   emeta  = (int2*)carve((size_t)E * 8);
  int2*   epair  = (int2*)carve((size_t)E * 8);
  int*    eid    = (int*)carve((size_t)E * 4);
  ushort* W1t    = (ushort*)carve((size_t)C * C * 2);
  ushort* Wth    = (ushort*)carve((size_t)10 * C * C * 2);
  ushort* Wtl    = (ushort*)carve((size_t)10 * C * C * 2);
  float*  big0   = (float*)carve((size_t)N * C * 4);
  float*  big1   = (float*)carve((size_t)N * C * 4);
  float*  big2   = (float*)carve((size_t)N * C * 4);

  hipMemsetAsync(cnt, 0, (size_t)N * 4, stream);
  k_degree<<<(E + 255) / 256, 256, 0, stream>>>(col, cnt, E);
  k_scan<<<1, 1024, 0, stream>>>(cnt, dis, indptr, cursor, N);
  k_csrfill<<<(E + 255) / 256, 256, 0, stream>>>(row, col, dis, cursor,
                                                 emeta, epair, eid, E);
  k_prepw<<<C * C / 256, 256, 0, stream>>>(fc1_W, W1t);
  k_prepw2<<<10 * C * C / 256, 256, 0, stream>>>(convs_W, fc0_W, Wth, Wtl);

  int layerBlocks = (N + 63) / 64;
  const int MSZ = C * C;

  // layer 0 (no skip)
  k_layer<<<layerBlocks, 256, 0, stream>>>(x, indptr, emeta, dis, Wth, Wtl,
                                           convs_b, nullptr, big0, N);
  float* hcur = big0; float* hoth = big1;
  for (int l = 1; l < L; ++l) {
    k_layer<<<layerBlocks, 256, 0, stream>>>(hcur, indptr, emeta, dis,
                                             Wth + (size_t)l * MSZ,
                                             Wtl + (size_t)l * MSZ,
                                             convs_b + (size_t)l * C, hcur,
                                             hoth, N);
    float* tmp = hcur; hcur = hoth; hoth = tmp;
  }
  // edge MLP: P = h@fc0_W[:128], Q = h@fc0_W[128:] + b0
  float* Pm = hoth;   // the non-final h buffer is free
  float* Qm = big2;
  k_gemm_mfma<<<layerBlocks, 256, 0, stream>>>(hcur, Wth + (size_t)8 * MSZ,
                                               Wtl + (size_t)8 * MSZ, nullptr,
                                               Pm, N);
  k_gemm_mfma<<<layerBlocks, 256, 0, stream>>>(hcur, Wth + (size_t)9 * MSZ,
                                               Wtl + (size_t)9 * MSZ, fc0_b,
                                               Qm, N);
  k_edge<<<(E + 63) / 64, 256, 0, stream>>>(Pm, Qm, epair, eid, W1t, fc1_b,
                                            fc2_W, fc2_b, out, E);
}

// Round 6
// 1959.679 us; speedup vs baseline: 1.3727x; 1.3727x over previous
//
#include <hip/hip_runtime.h>

#define C 128

typedef __attribute__((ext_vector_type(8))) short short8v;
typedef __attribute__((ext_vector_type(4))) float float4v;

__device__ __forceinline__ ushort f2bf(float f) {
  union { float f; uint u; } v; v.f = f;
  uint u = v.u;
  return (ushort)((u + 0x7FFF + ((u >> 16) & 1)) >> 16);  // RNE
}
__device__ __forceinline__ float bf2f(ushort s) {
  union { uint u; float f; } v; v.u = ((uint)s) << 16; return v.f;
}

// LDS swizzles: row-stride 128 shorts (16 chunks of 8) / 64 shorts (8 chunks)
__device__ __forceinline__ short* swz(short* base, int row, int chunk) {
  return base + row * 128 + ((chunk ^ (row & 15)) << 3);
}
__device__ __forceinline__ short* swz8(short* base, int row, int chunk) {
  return base + row * 64 + ((chunk ^ (row & 7)) << 3);
}

// ---------------- degree count ------------------------------------------
__global__ void k_degree(const int* __restrict__ col, int* __restrict__ cnt, int E) {
  int e = blockIdx.x * blockDim.x + threadIdx.x;
  if (e < E) atomicAdd(&cnt[col[e]], 1);
}

// ---------------- single-block scan: deg -> dis, indptr, cursor --------
__global__ void k_scan(const int* __restrict__ cnt, float* __restrict__ dis,
                       int* __restrict__ indptr, int* __restrict__ cursor, int N) {
  __shared__ int sb[1024];
  int t = threadIdx.x;
  int chunk = (N + 1023) >> 10;
  int lo = t * chunk, hi = min(lo + chunk, N);
  int sum = 0;
  for (int i = lo; i < hi; ++i) sum += cnt[i];
  sb[t] = sum;
  __syncthreads();
  for (int off = 1; off < 1024; off <<= 1) {
    int v = (t >= off) ? sb[t - off] : 0;
    __syncthreads();
    sb[t] += v;
    __syncthreads();
  }
  int run = sb[t] - sum;
  for (int i = lo; i < hi; ++i) {
    indptr[i] = run; cursor[i] = run;
    dis[i] = rsqrtf((float)(cnt[i] + 1));
    run += cnt[i];
  }
  if (lo < N && hi == N) indptr[N] = run;
}

// ---------------- CSR fill: dst-sorted meta + inverse permutation -------
__global__ void k_csrfill(const int* __restrict__ row, const int* __restrict__ col,
                          const float* __restrict__ dis, int* __restrict__ cursor,
                          int2* __restrict__ emeta, int2* __restrict__ epair,
                          int* __restrict__ inv, int E) {
  int e = blockIdx.x * blockDim.x + threadIdx.x;
  if (e >= E) return;
  int r = row[e], c = col[e];
  int pos = atomicAdd(&cursor[c], 1);
  float nrm = dis[r] * dis[c];
  emeta[pos] = make_int2(r, __float_as_int(nrm));
  epair[pos] = make_int2(r, c);
  inv[e] = pos;           // coalesced by e; k_perm gathers tmp[inv[e]]
}

// ---------------- W1^T -> bf16 (fc1, hi only) ---------------------------
__global__ void k_prepw(const float* __restrict__ W1, ushort* __restrict__ W1t) {
  int idx = blockIdx.x * 256 + threadIdx.x;  // 16384
  int n = idx >> 7, k = idx & 127;
  W1t[idx] = f2bf(W1[k * C + n]);
}

// ---------------- conv/fc0 W^T -> bf16 hi/lo (10 matrices) --------------
__global__ void k_prepw2(const float* __restrict__ convs_W,
                         const float* __restrict__ fc0_W,
                         ushort* __restrict__ Wth, ushort* __restrict__ Wtl) {
  int g = blockIdx.x * 256 + threadIdx.x;  // [0, 10*16384)
  int mat = g >> 14, idx = g & 16383;
  int n = idx >> 7, k = idx & 127;
  const float* src = (mat < 8) ? convs_W + ((size_t)mat << 14)
                               : fc0_W + ((size_t)(mat - 8) << 14);
  float v = src[k * C + n];
  ushort h = f2bf(v);
  Wth[g] = h;
  Wtl[g] = f2bf(v - bf2f(h));
}

// ---------------- aggregation: agg[v] = sum norm*h[src] + dis^2*h[v] ----
// one wave per node, lane covers 2 channels; 8 edge rows in flight
__global__ __launch_bounds__(256)
void k_agg(const float* __restrict__ h, const int* __restrict__ indptr,
           const int2* __restrict__ emeta, const float* __restrict__ dis,
           float* __restrict__ agg, int N) {
  int w = (blockIdx.x * 256 + threadIdx.x) >> 6;
  int lane = threadIdx.x & 63;
  if (w >= N) return;
  int s = indptr[w], e = indptr[w + 1];
  float ax = 0.f, ay = 0.f;
  int i = s;
  for (; i + 8 <= e; i += 8) {  // 8 independent row loads in flight
    int2 m[8];
#pragma unroll
    for (int u = 0; u < 8; ++u) m[u] = emeta[i + u];
    float2 hv[8];
#pragma unroll
    for (int u = 0; u < 8; ++u)
      hv[u] = *(const float2*)(h + (size_t)m[u].x * C + lane * 2);
#pragma unroll
    for (int u = 0; u < 8; ++u) {
      float nn = __int_as_float(m[u].y);
      ax += nn * hv[u].x; ay += nn * hv[u].y;
    }
  }
  for (; i < e; ++i) {
    int2 m0 = emeta[i];
    float2 h0 = *(const float2*)(h + (size_t)m0.x * C + lane * 2);
    float n0 = __int_as_float(m0.y);
    ax += n0 * h0.x; ay += n0 * h0.y;
  }
  float dv = dis[w];
  float2 hs = *(const float2*)(h + (size_t)w * C + lane * 2);
  ax += dv * dv * hs.x; ay += dv * dv * hs.y;
  float2 o; o.x = ax; o.y = ay;
  *(float2*)(agg + (size_t)w * C + lane * 2) = o;
}

// ---------------- MFMA GEMM: out[M,128] = op(A[M,128] @ W) --------------
// A fp32 -> hi/lo bf16 in LDS (swizzled); W^T bf16 hi/lo staged in k-halves.
// 3-term hi/lo product = fp32-equivalent. LDS 64KB -> 2 blocks/CU.
__global__ __launch_bounds__(256, 2)
void k_gemm_mfma(const float* __restrict__ A, const ushort* __restrict__ Wth,
                 const ushort* __restrict__ Wtl, const float* __restrict__ bias,
                 const float* __restrict__ skip, float* __restrict__ out,
                 int M, int relu) {
  __shared__ __align__(16) short Ah[64 * 128];
  __shared__ __align__(16) short Al[64 * 128];
  __shared__ __align__(16) short Wh[128 * 64];
  __shared__ __align__(16) short Wl[128 * 64];
  int t = threadIdx.x;
  int r0 = blockIdx.x * 64;
  {
    int rl = t >> 2, p = t & 3;
    int r = r0 + rl;
    const float* Ar = A + (size_t)r * C + p * 32;
#pragma unroll
    for (int i = 0; i < 4; ++i) {
      float v[8];
      if (r < M) {
        float4 a0 = *(const float4*)(Ar + 8 * i);
        float4 a1 = *(const float4*)(Ar + 8 * i + 4);
        v[0] = a0.x; v[1] = a0.y; v[2] = a0.z; v[3] = a0.w;
        v[4] = a1.x; v[5] = a1.y; v[6] = a1.z; v[7] = a1.w;
      } else {
#pragma unroll
        for (int j = 0; j < 8; ++j) v[j] = 0.f;
      }
      short8v hi, lo;
#pragma unroll
      for (int j = 0; j < 8; ++j) {
        ushort hh = f2bf(v[j]);
        hi[j] = (short)hh;
        lo[j] = (short)f2bf(v[j] - bf2f(hh));
      }
      *(short8v*)swz(Ah, rl, p * 4 + i) = hi;
      *(short8v*)swz(Al, rl, p * 4 + i) = lo;
    }
  }
  int w = t >> 6, lane = t & 63;
  int m0 = w * 16;
  int lm = lane & 15, lq = lane >> 4;
  float4v acc[8];
#pragma unroll
  for (int j = 0; j < 8; ++j) acc[j] = (float4v){0.f, 0.f, 0.f, 0.f};

  for (int half = 0; half < 2; ++half) {
    __syncthreads();
    {
#pragma unroll
      for (int i = 0; i < 4; ++i) {
        int g = i * 256 + t;
        int n = g >> 3, kc = g & 7;
        size_t off = (size_t)n * 128 + half * 64 + kc * 8;
        *(short8v*)swz8(Wh, n, kc) = *(const short8v*)(Wth + off);
        *(short8v*)swz8(Wl, n, kc) = *(const short8v*)(Wtl + off);
      }
    }
    __syncthreads();
#pragma unroll
    for (int kk = 0; kk < 2; ++kk) {
      int ach = (half * 2 + kk) * 4 + lq;
      int wch = kk * 4 + lq;
      short8v ah = *(const short8v*)swz(Ah, m0 + lm, ach);
      short8v al = *(const short8v*)swz(Al, m0 + lm, ach);
#pragma unroll
      for (int j = 0; j < 8; ++j) {
        short8v bh = *(const short8v*)swz8(Wh, j * 16 + lm, wch);
        short8v bl = *(const short8v*)swz8(Wl, j * 16 + lm, wch);
        acc[j] = __builtin_amdgcn_mfma_f32_16x16x32_bf16(ah, bh, acc[j], 0, 0, 0);
        acc[j] = __builtin_amdgcn_mfma_f32_16x16x32_bf16(al, bh, acc[j], 0, 0, 0);
        acc[j] = __builtin_amdgcn_mfma_f32_16x16x32_bf16(ah, bl, acc[j], 0, 0, 0);
      }
    }
  }
#pragma unroll
  for (int j = 0; j < 8; ++j) {
    int n = j * 16 + lm;
    float bv = bias ? bias[n] : 0.f;
#pragma unroll
    for (int r = 0; r < 4; ++r) {
      int m = r0 + m0 + lq * 4 + r;
      if (m >= M) continue;
      float v = acc[j][r] + bv;
      if (skip) v += skip[(size_t)m * C + n];
      if (relu) v = fmaxf(v, 0.f);
      out[(size_t)m * C + n] = v;
    }
  }
}

// ---------------- fused edge MLP (CSR order, coalesced tmp out) ----------
__global__ __launch_bounds__(256, 2)
void k_edge(const float* __restrict__ P, const float* __restrict__ Q,
            const int2* __restrict__ epair, const ushort* __restrict__ W1t,
            const float* __restrict__ b1, const float* __restrict__ w2,
            const float* __restrict__ b2, float* __restrict__ tmpout, int E) {
  __shared__ __align__(16) short EtH[64 * 128];
  __shared__ __align__(16) short EtL[64 * 128];
  __shared__ __align__(16) short Wl[128 * 128];
  int t = threadIdx.x;
  int p0 = blockIdx.x * 64;
  {
    int el = t >> 2, p4 = t & 3;
    int p = p0 + el;
    if (p >= E) p = E - 1;
    int2 rc = epair[p];
    const float* Pp = P + (size_t)rc.x * C + p4 * 32;
    const float* Qp = Q + (size_t)rc.y * C + p4 * 32;
#pragma unroll
    for (int i = 0; i < 4; ++i) {
      float4 a0 = *(const float4*)(Pp + 8 * i);
      float4 a1 = *(const float4*)(Pp + 8 * i + 4);
      float4 b0 = *(const float4*)(Qp + 8 * i);
      float4 b1v4 = *(const float4*)(Qp + 8 * i + 4);
      float v[8] = {a0.x + b0.x, a0.y + b0.y, a0.z + b0.z, a0.w + b0.w,
                    a1.x + b1v4.x, a1.y + b1v4.y, a1.z + b1v4.z, a1.w + b1v4.w};
      short8v hi, lo;
#pragma unroll
      for (int j = 0; j < 8; ++j) {
        float f = fmaxf(v[j], 0.f);
        ushort h = f2bf(f);
        hi[j] = (short)h;
        lo[j] = (short)f2bf(f - bf2f(h));
      }
      *(short8v*)swz(EtH, el, p4 * 4 + i) = hi;
      *(short8v*)swz(EtL, el, p4 * 4 + i) = lo;
    }
  }
  {
#pragma unroll
    for (int i = 0; i < 8; ++i) {
      int g = i * 256 + t;
      int r = g >> 4, c = g & 15;
      short8v wv = *(const short8v*)(W1t + g * 8);
      *(short8v*)swz(Wl, r, c) = wv;
    }
  }
  __syncthreads();

  int w = t >> 6, lane = t & 63;
  int m0 = w * 16;
  int lm = lane & 15, lq = lane >> 4;
  float4v acc[8];
#pragma unroll
  for (int j = 0; j < 8; ++j) acc[j] = (float4v){0.f, 0.f, 0.f, 0.f};

#pragma unroll
  for (int kk = 0; kk < 4; ++kk) {
    int ch = kk * 4 + lq;
    short8v ah = *(const short8v*)swz(EtH, m0 + lm, ch);
    short8v al = *(const short8v*)swz(EtL, m0 + lm, ch);
#pragma unroll
    for (int j = 0; j < 8; ++j) {
      short8v b = *(const short8v*)swz(Wl, j * 16 + lm, ch);
      acc[j] = __builtin_amdgcn_mfma_f32_16x16x32_bf16(ah, b, acc[j], 0, 0, 0);
      acc[j] = __builtin_amdgcn_mfma_f32_16x16x32_bf16(al, b, acc[j], 0, 0, 0);
    }
  }

  float partv[4] = {0.f, 0.f, 0.f, 0.f};
#pragma unroll
  for (int j = 0; j < 8; ++j) {
    int n = j * 16 + lm;
    float b1v = b1[n], w2v = w2[n];
#pragma unroll
    for (int r = 0; r < 4; ++r) {
      float e2 = fmaxf(acc[j][r] + b1v, 0.f);
      partv[r] = fmaf(e2, w2v, partv[r]);
    }
  }
#pragma unroll
  for (int off = 1; off < 16; off <<= 1) {
#pragma unroll
    for (int r = 0; r < 4; ++r) partv[r] += __shfl_xor(partv[r], off, 64);
  }
  if (lm == 0) {
    float bb = b2[0];
#pragma unroll
    for (int r = 0; r < 4; ++r) {
      int p = p0 + m0 + lq * 4 + r;
      if (p < E) tmpout[p] = partv[r] + bb;  // coalesced (CSR order)
    }
  }
}

// ---------------- permute: out[e] = tmp[inv[e]] (coalesced write) --------
__global__ void k_perm(const float* __restrict__ tmp, const int* __restrict__ inv,
                       float* __restrict__ out, int E) {
  int e = blockIdx.x * 256 + threadIdx.x;
  if (e < E) out[e] = tmp[inv[e]];  // gather from L2-resident 6.4MB
}

// ---------------- host ---------------------------------------------------
extern "C" void kernel_launch(void* const* d_in, const int* in_sizes, int n_in,
                              void* d_out, int out_size, void* d_ws, size_t ws_size,
                              hipStream_t stream) {
  const float* x       = (const float*)d_in[0];
  const int*   ei      = (const int*)d_in[1];
  const float* convs_W = (const float*)d_in[2];
  const float* convs_b = (const float*)d_in[3];
  const float* fc0_W   = (const float*)d_in[4];
  const float* fc0_b   = (const float*)d_in[5];
  const float* fc1_W   = (const float*)d_in[6];
  const float* fc1_b   = (const float*)d_in[7];
  const float* fc2_W   = (const float*)d_in[8];
  const float* fc2_b   = (const float*)d_in[9];
  float* out = (float*)d_out;

  const int N = in_sizes[0] / C;        // 50000
  const int E = in_sizes[1] / 2;        // 1600000
  const int L = in_sizes[2] / (C * C);  // 8
  const int* row = ei;
  const int* col = ei + E;

  char* wp = (char*)d_ws;
  auto carve = [&](size_t bytes) {
    char* p = wp; wp += (bytes + 255) & ~(size_t)255; return p;
  };
  int*    cnt    = (int*)carve((size_t)N * 4);
  int*    indptr = (int*)carve((size_t)(N + 1) * 4);
  int*    cursor = (int*)carve((size_t)N * 4);
  float*  dis    = (float*)carve((size_t)N * 4);
  int2*   emeta  = (int2*)carve((size_t)E * 8);
  int2*   epair  = (int2*)carve((size_t)E * 8);
  int*    inv    = (int*)carve((size_t)E * 4);
  float*  tmpout = (float*)carve((size_t)E * 4);
  ushort* W1t    = (ushort*)carve((size_t)C * C * 2);
  ushort* Wth    = (ushort*)carve((size_t)10 * C * C * 2);
  ushort* Wtl    = (ushort*)carve((size_t)10 * C * C * 2);
  float*  big0   = (float*)carve((size_t)N * C * 4);
  float*  big1   = (float*)carve((size_t)N * C * 4);
  float*  big2   = (float*)carve((size_t)N * C * 4);

  hipMemsetAsync(cnt, 0, (size_t)N * 4, stream);
  k_degree<<<(E + 255) / 256, 256, 0, stream>>>(col, cnt, E);
  k_scan<<<1, 1024, 0, stream>>>(cnt, dis, indptr, cursor, N);
  k_csrfill<<<(E + 255) / 256, 256, 0, stream>>>(row, col, dis, cursor,
                                                 emeta, epair, inv, E);
  k_prepw<<<C * C / 256, 256, 0, stream>>>(fc1_W, W1t);
  k_prepw2<<<10 * C * C / 256, 256, 0, stream>>>(convs_W, fc0_W, Wth, Wtl);

  int aggBlocks  = (N * 64 + 255) / 256;
  int gemmBlocks = (N + 63) / 64;
  const int MSZ = C * C;

  // layer 0 (no skip)
  k_agg<<<aggBlocks, 256, 0, stream>>>(x, indptr, emeta, dis, big1, N);
  k_gemm_mfma<<<gemmBlocks, 256, 0, stream>>>(big1, Wth, Wtl, convs_b, nullptr,
                                              big0, N, 1);
  float* hcur = big0; float* fA = big1; float* fB = big2;
  for (int l = 1; l < L; ++l) {
    k_agg<<<aggBlocks, 256, 0, stream>>>(hcur, indptr, emeta, dis, fA, N);
    k_gemm_mfma<<<gemmBlocks, 256, 0, stream>>>(fA, Wth + (size_t)l * MSZ,
                                                Wtl + (size_t)l * MSZ,
                                                convs_b + (size_t)l * C, hcur,
                                                fB, N, 1);
    float* tmp = hcur; hcur = fB; fB = tmp;
  }
  // edge MLP: P = h@fc0_W[:128], Q = h@fc0_W[128:] + b0
  float* Pm = fA; float* Qm = fB;
  k_gemm_mfma<<<gemmBlocks, 256, 0, stream>>>(hcur, Wth + (size_t)8 * MSZ,
                                              Wtl + (size_t)8 * MSZ, nullptr,
                                              nullptr, Pm, N, 0);
  k_gemm_mfma<<<gemmBlocks, 256, 0, stream>>>(hcur, Wth + (size_t)9 * MSZ,
                                              Wtl + (size_t)9 * MSZ, fc0_b,
                                              nullptr, Qm, N, 0);
  k_edge<<<(E + 63) / 64, 256, 0, stream>>>(Pm, Qm, epair, W1t, fc1_b,
                                            fc2_W, fc2_b, tmpout, E);
  k_perm<<<(E + 255) / 256, 256, 0, stream>>>(tmpout, inv, out, E);
}